// Round 22
// baseline (262.933 us; speedup 1.0000x reference)
//
#include <hip/hip_runtime.h>
#include <hip/hip_fp16.h>

#define NN 100000
#define NE 1200000
#define NBUK ((NN + 127) / 128)   // 782
#define NCHUNK 512                // chunks in bucket passes

typedef _Float16 h8 __attribute__((ext_vector_type(8)));
typedef float f32x4 __attribute__((ext_vector_type(4)));
typedef float f32x2 __attribute__((ext_vector_type(2)));

// ---------------- deterministic two-phase bucketed CSR build ----------------
__global__ __launch_bounds__(256) void k_bucketA(const int* __restrict__ col,
                                                 int* __restrict__ blkcnt) {
    __shared__ int lh[NBUK];
    const int tid = threadIdx.x;
    const int per = (NE + NCHUNK - 1) / NCHUNK;
    const int e0 = blockIdx.x * per;
    const int e1 = (e0 + per < NE) ? (e0 + per) : NE;
    for (int i = tid; i < NBUK; i += 256) lh[i] = 0;
    __syncthreads();
    for (int e = e0 + tid; e < e1; e += 256)
        atomicAdd(&lh[col[e] >> 7], 1);
    __syncthreads();
    for (int b = tid; b < NBUK; b += 256)
        blkcnt[b * NCHUNK + blockIdx.x] = lh[b];
}

__global__ __launch_bounds__(512) void k_colscan(int* __restrict__ blkcnt, int* __restrict__ bcnt) {
    __shared__ int s[NCHUNK];
    const int b = blockIdx.x, tid = threadIdx.x;
    int v = blkcnt[b * NCHUNK + tid];
    s[tid] = v;
    __syncthreads();
    #pragma unroll
    for (int d = 1; d < NCHUNK; d <<= 1) {
        int t = (tid >= d) ? s[tid - d] : 0;
        __syncthreads();
        s[tid] += t;
        __syncthreads();
    }
    blkcnt[b * NCHUNK + tid] = s[tid] - v;   // exclusive prefix within bucket
    if (tid == NCHUNK - 1) bcnt[b] = s[NCHUNK - 1];
}

__global__ __launch_bounds__(1024) void k_bscan(int* __restrict__ bcnt) {
    __shared__ int s[1024];
    int tid = threadIdx.x;
    int v = (tid < NBUK) ? bcnt[tid] : 0;
    s[tid] = v;
    __syncthreads();
    #pragma unroll
    for (int d = 1; d < 1024; d <<= 1) {
        int t = (tid >= d) ? s[tid - d] : 0;
        __syncthreads();
        s[tid] += t;
        __syncthreads();
    }
    if (tid < NBUK) bcnt[tid] = s[tid] - v;
    if (tid == 0) bcnt[NBUK] = NE;
}

__global__ __launch_bounds__(256) void k_bucketB(const int* __restrict__ row,
                                                 const int* __restrict__ col,
                                                 const int* __restrict__ bbase,
                                                 const int* __restrict__ blkcnt,
                                                 unsigned* __restrict__ tmp) {
    __shared__ int lh[NBUK];
    const int tid = threadIdx.x;
    const int per = (NE + NCHUNK - 1) / NCHUNK;
    const int e0 = blockIdx.x * per;
    const int e1 = (e0 + per < NE) ? (e0 + per) : NE;
    for (int b = tid; b < NBUK; b += 256)
        lh[b] = bbase[b] + blkcnt[b * NCHUNK + blockIdx.x];
    __syncthreads();
    for (int e = e0 + tid; e < e1; e += 256) {
        int c = col[e], r = row[e];
        int pos = atomicAdd(&lh[c >> 7], 1);
        tmp[pos] = ((unsigned)r << 7) | (unsigned)(c & 127);
    }
}

__global__ __launch_bounds__(256) void k_build(const unsigned* __restrict__ tmp,
                                               const int* __restrict__ bbase,
                                               int* __restrict__ off,
                                               float* __restrict__ dinv,
                                               int* __restrict__ csr_row) {
    __shared__ int cnt[128], s[128], cur[128];
    const int b = blockIdx.x, tid = threadIdx.x;
    const int colBase = b << 7;
    const int nCols = (NN - colBase < 128) ? (NN - colBase) : 128;
    const int seg0 = bbase[b], seg1 = bbase[b + 1];
    if (tid < 128) cnt[tid] = 0;
    __syncthreads();
    for (int i = seg0 + tid; i < seg1; i += 256)
        atomicAdd(&cnt[tmp[i] & 127], 1);
    __syncthreads();
    if (tid < 128) s[tid] = cnt[tid];
    __syncthreads();
    #pragma unroll
    for (int d = 1; d < 128; d <<= 1) {
        int t = (tid < 128 && tid >= d) ? s[tid - d] : 0;
        __syncthreads();
        if (tid < 128) s[tid] += t;
        __syncthreads();
    }
    if (tid < nCols) {
        int exc = seg0 + s[tid] - cnt[tid];
        off[colBase + tid] = exc;
        cur[tid] = exc;
        dinv[colBase + tid] = rsqrtf((float)cnt[tid] + 1.0f);
    }
    if (b == 0 && tid == 0) off[NN] = NE;
    __syncthreads();
    for (int i = seg0 + tid; i < seg1; i += 256) {
        unsigned v = tmp[i];
        int pos = atomicAdd(&cur[v & 127u], 1);
        csr_row[pos] = (int)(v >> 7);
    }
}

// ---------------- fused proj + byp + conv1 GEMM ----------------
__global__ __launch_bounds__(256) void k_gemmPC(const float* __restrict__ X,
                                                const float* __restrict__ W,
                                                const float* __restrict__ bias,
                                                _Float16* __restrict__ Yh,
                                                const float* __restrict__ bypW,
                                                const float* __restrict__ bypb,
                                                float* __restrict__ bypOut,
                                                const float* __restrict__ convW1,
                                                const float* __restrict__ dinv,
                                                unsigned char* __restrict__ Y8,
                                                int n_nodes) {
    constexpr int D = 128, RS = D + 8, KS = D / 32;
    constexpr int RS2 = 72;               // hA tile row stride (halfs)
    __shared__ _Float16 Xh[64 * RS];
    __shared__ _Float16 Wh[64 * RS];
    const int tid = threadIdx.x;
    const int n0 = blockIdx.x * 64;

    for (int i = tid; i < 64 * (D / 8); i += 256) {
        int j = i / (D / 8), d8 = (i % (D / 8)) * 8;
        const float4* wp = (const float4*)&W[j * D + d8];
        float4 w0 = wp[0], w1 = wp[1];
        h8 h = { (_Float16)w0.x, (_Float16)w0.y, (_Float16)w0.z, (_Float16)w0.w,
                 (_Float16)w1.x, (_Float16)w1.y, (_Float16)w1.z, (_Float16)w1.w };
        *(h8*)&Wh[j * RS + d8] = h;
    }
    for (int i = tid; i < 64 * (D / 8); i += 256) {
        int nl = i / (D / 8), d8 = (i % (D / 8)) * 8;
        int n = n0 + nl; if (n >= n_nodes) n = n_nodes - 1;
        const float4* xp = (const float4*)&X[(size_t)n * D + d8];
        float4 x0 = xp[0], x1 = xp[1];
        h8 h = { (_Float16)x0.x, (_Float16)x0.y, (_Float16)x0.z, (_Float16)x0.w,
                 (_Float16)x1.x, (_Float16)x1.y, (_Float16)x1.z, (_Float16)x1.w };
        *(h8*)&Xh[nl * RS + d8] = h;
    }
    __syncthreads();

    const int wid = tid >> 6, lane = tid & 63;
    const int lm = lane & 15, lq = lane >> 4;
    const int mBase = wid * 16;

    h8 bfrag[4][KS];
    #pragma unroll
    for (int t = 0; t < 4; ++t)
        #pragma unroll
        for (int s = 0; s < KS; ++s)
            bfrag[t][s] = *(const h8*)&Wh[(t * 16 + lm) * RS + s * 32 + lq * 8];

    h8 bfragB[KS];
    #pragma unroll
    for (int s = 0; s < KS; ++s) {
        if (lm < 3) {
            const float4* wp = (const float4*)&bypW[lm * D + s * 32 + lq * 8];
            float4 w0 = wp[0], w1 = wp[1];
            bfragB[s] = (h8){ (_Float16)w0.x, (_Float16)w0.y, (_Float16)w0.z, (_Float16)w0.w,
                              (_Float16)w1.x, (_Float16)w1.y, (_Float16)w1.z, (_Float16)w1.w };
        } else {
            bfragB[s] = (h8)(_Float16)0;
        }
    }

    f32x4 acc[5] = {};
    #pragma unroll
    for (int s = 0; s < KS; ++s) {
        h8 a = *(const h8*)&Xh[(mBase + lm) * RS + s * 32 + lq * 8];
        #pragma unroll
        for (int t = 0; t < 4; ++t)
            acc[t] = __builtin_amdgcn_mfma_f32_16x16x32_f16(a, bfrag[t][s], acc[t], 0, 0, 0);
        acc[4] = __builtin_amdgcn_mfma_f32_16x16x32_f16(a, bfragB[s], acc[4], 0, 0, 0);
    }

    float bb[4];
    #pragma unroll
    for (int t = 0; t < 4; ++t) bb[t] = bias[t * 16 + lm];
    float bypbv = (lm < 3) ? bypb[lm] : 0.f;
    const int nodeBase = n0 + mBase + lq * 4;

    __syncthreads();   // all waves done reading Xh/Wh; safe to repurpose

    #pragma unroll
    for (int r = 0; r < 4; ++r) {
        int node = nodeBase + r;
        int nloc = mBase + lq * 4 + r;
        #pragma unroll
        for (int t = 0; t < 4; ++t) {
            _Float16 hv = (_Float16)(acc[t][r] + bb[t]);
            Xh[nloc * RS2 + t * 16 + lm] = hv;            // stash tile
            if (node < n_nodes)
                Yh[(size_t)node * 64 + t * 16 + lm] = hv;
        }
        if (node < n_nodes && lm < 3)
            bypOut[node * 3 + lm] = acc[4][r] + bypbv;
    }
    for (int i = tid; i < 64 * 8; i += 256) {
        int j = i >> 3, d8 = (i & 7) * 8;
        const float4* wp = (const float4*)&convW1[j * 64 + d8];
        float4 w0 = wp[0], w1 = wp[1];
        h8 h = { (_Float16)w0.x, (_Float16)w0.y, (_Float16)w0.z, (_Float16)w0.w,
                 (_Float16)w1.x, (_Float16)w1.y, (_Float16)w1.z, (_Float16)w1.w };
        *(h8*)&Wh[j * RS2 + d8] = h;
    }
    __syncthreads();

    h8 cfrag[4][2];
    #pragma unroll
    for (int t = 0; t < 4; ++t)
        #pragma unroll
        for (int s = 0; s < 2; ++s)
            cfrag[t][s] = *(const h8*)&Wh[(t * 16 + lm) * RS2 + s * 32 + lq * 8];

    f32x4 acc2[4] = {};
    #pragma unroll
    for (int s = 0; s < 2; ++s) {
        h8 a = *(const h8*)&Xh[(mBase + lm) * RS2 + s * 32 + lq * 8];
        #pragma unroll
        for (int t = 0; t < 4; ++t)
            acc2[t] = __builtin_amdgcn_mfma_f32_16x16x32_f16(a, cfrag[t][s], acc2[t], 0, 0, 0);
    }
    #pragma unroll
    for (int r = 0; r < 4; ++r) {
        int node = nodeBase + r;
        if (node < n_nodes) {
            float sdv = dinv[node];
            #pragma unroll
            for (int t = 0; t < 4; ++t) {
                float v = acc2[t][r] * sdv;
                int pk = __builtin_amdgcn_cvt_pk_fp8_f32(v, v, 0, false);
                Y8[(size_t)node * 64 + t * 16 + lm] = (unsigned char)(pk & 0xff);
            }
        }
    }
}

// ---------------- conv GEMM (D=64): fp8 e4m3 message output only ----------------
__global__ __launch_bounds__(256) void k_gemmC(const _Float16* __restrict__ Xhg,
                                               const float* __restrict__ W,
                                               const float* __restrict__ dinv,
                                               unsigned char* __restrict__ Y8,
                                               int n_nodes) {
    constexpr int D = 64, RS = D + 8, KS = D / 32;
    __shared__ _Float16 Xh[64 * RS];
    __shared__ _Float16 Wh[64 * RS];
    const int tid = threadIdx.x;
    const int n0 = blockIdx.x * 64;

    for (int i = tid; i < 64 * (D / 8); i += 256) {
        int j = i / (D / 8), d8 = (i % (D / 8)) * 8;
        const float4* wp = (const float4*)&W[j * D + d8];
        float4 w0 = wp[0], w1 = wp[1];
        h8 h = { (_Float16)w0.x, (_Float16)w0.y, (_Float16)w0.z, (_Float16)w0.w,
                 (_Float16)w1.x, (_Float16)w1.y, (_Float16)w1.z, (_Float16)w1.w };
        *(h8*)&Wh[j * RS + d8] = h;
    }
    for (int i = tid; i < 64 * (D / 8); i += 256) {
        int nl = i / (D / 8), d8 = (i % (D / 8)) * 8;
        int n = n0 + nl; if (n >= n_nodes) n = n_nodes - 1;
        *(h8*)&Xh[nl * RS + d8] = *(const h8*)&Xhg[(size_t)n * D + d8];
    }
    __syncthreads();

    const int wid = tid >> 6, lane = tid & 63;
    const int lm = lane & 15, lq = lane >> 4;
    const int mBase = wid * 16;

    h8 bfrag[4][KS];
    #pragma unroll
    for (int t = 0; t < 4; ++t)
        #pragma unroll
        for (int s = 0; s < KS; ++s)
            bfrag[t][s] = *(const h8*)&Wh[(t * 16 + lm) * RS + s * 32 + lq * 8];

    f32x4 acc[4] = {};
    #pragma unroll
    for (int s = 0; s < KS; ++s) {
        h8 a = *(const h8*)&Xh[(mBase + lm) * RS + s * 32 + lq * 8];
        #pragma unroll
        for (int t = 0; t < 4; ++t)
            acc[t] = __builtin_amdgcn_mfma_f32_16x16x32_f16(a, bfrag[t][s], acc[t], 0, 0, 0);
    }

    const int nodeBase = n0 + mBase + lq * 4;
    #pragma unroll
    for (int r = 0; r < 4; ++r) {
        int node = nodeBase + r;
        if (node < n_nodes) {
            float sdv = dinv[node];
            #pragma unroll
            for (int t = 0; t < 4; ++t) {
                float v = acc[t][r] * sdv;
                int pk = __builtin_amdgcn_cvt_pk_fp8_f32(v, v, 0, false);
                Y8[(size_t)node * 64 + t * 16 + lm] = (unsigned char)(pk & 0xff);
            }
        }
    }
}

// ---------------- pull-aggregation: 4 nodes/wave, 2 edge-parity groups x 8 octets ----------------
// lane = (node2 = lane>>4, parity = (lane>>3)&1, oct = lane&7). Parity p covers edges
// {p*8+q + 16k}; one shfl_xor(8) merges parities. Halves the per-lane serial chain.
template<bool RES, bool HEAD>
__global__ __launch_bounds__(256) void k_gather(const unsigned char* __restrict__ hB8,
                                                const float* __restrict__ dinv,
                                                const int* __restrict__ off,
                                                const int* __restrict__ csr_row,
                                                const float* __restrict__ convb,
                                                const float* __restrict__ bng,
                                                const float* __restrict__ bnb,
                                                _Float16* __restrict__ hA,
                                                const float* __restrict__ byp,
                                                const float* __restrict__ headW,
                                                const float* __restrict__ headb,
                                                float* __restrict__ out) {
    __shared__ float HWs[HEAD ? 204 : 1];
    const int tid = threadIdx.x;
    if constexpr (HEAD) {
        for (int i = tid; i < 204; i += 256)
            HWs[i] = (i < 201) ? headW[i] : headb[i - 201];
        __syncthreads();
    }
    const int wid = tid >> 6, lane = tid & 63;
    const int n = blockIdx.x * 16 + wid * 4 + (lane >> 4);   // grid = NN/16 exactly
    const int par = (lane >> 3) & 1;
    const int oct = lane & 7;
    const int f0 = oct * 8;

    const int e0 = off[n], eEnd = off[n + 1];
    const int deg = eEnd - e0;
    int m = deg;   // wave-max degree over the 4 node-groups (lanes differ in bits 4,5)
    #pragma unroll
    for (int mask = 16; mask < 64; mask <<= 1) {
        int o = __shfl_xor(m, mask, 64);
        m = (o > m) ? o : m;
    }

    const uint2* rows8 = (const uint2*)hB8;   // 8 uint2 per node row
    float acc[8] = {0, 0, 0, 0, 0, 0, 0, 0};
    if (par == 0) {   // self-loop term added once
        uint2 selfw = rows8[(size_t)n * 8 + oct];
        f32x2 p0 = __builtin_amdgcn_cvt_pk_f32_fp8(selfw.x, false);
        f32x2 p1 = __builtin_amdgcn_cvt_pk_f32_fp8(selfw.x, true);
        f32x2 p2 = __builtin_amdgcn_cvt_pk_f32_fp8(selfw.y, false);
        f32x2 p3 = __builtin_amdgcn_cvt_pk_f32_fp8(selfw.y, true);
        acc[0] += p0.x; acc[1] += p0.y; acc[2] += p1.x; acc[3] += p1.y;
        acc[4] += p2.x; acc[5] += p2.y; acc[6] += p3.x; acc[7] += p3.y;
    }
    for (int it = par * 8; it < m; it += 16) {
        uint2 w[8];
        #pragma unroll
        for (int q = 0; q < 8; ++q) {
            bool vq = it + q < deg;
            int rq = csr_row[vq ? e0 + it + q : 0];
            w[q] = rows8[(size_t)rq * 8 + oct];
            if (!vq) { w[q].x = 0; w[q].y = 0; }
        }
        #pragma unroll
        for (int q = 0; q < 8; ++q) {
            f32x2 p0 = __builtin_amdgcn_cvt_pk_f32_fp8(w[q].x, false);
            f32x2 p1 = __builtin_amdgcn_cvt_pk_f32_fp8(w[q].x, true);
            f32x2 p2 = __builtin_amdgcn_cvt_pk_f32_fp8(w[q].y, false);
            f32x2 p3 = __builtin_amdgcn_cvt_pk_f32_fp8(w[q].y, true);
            acc[0] += p0.x; acc[1] += p0.y; acc[2] += p1.x; acc[3] += p1.y;
            acc[4] += p2.x; acc[5] += p2.y; acc[6] += p3.x; acc[7] += p3.y;
        }
    }
    // merge the two parity groups (lanes differ in bit 3)
    #pragma unroll
    for (int j = 0; j < 8; ++j) {
        int ai = __float_as_int(acc[j]);
        acc[j] += __int_as_float(__shfl_xor(ai, 8, 64));
    }

    const float dv = dinv[n];
    const float bnscale = rsqrtf(1.0f + 1e-5f);
    const float4 cb0 = *(const float4*)&convb[f0], cb1 = *(const float4*)&convb[f0 + 4];
    const float4 g0  = *(const float4*)&bng[f0],  g1  = *(const float4*)&bng[f0 + 4];
    const float4 b0_ = *(const float4*)&bnb[f0],  b1_ = *(const float4*)&bnb[f0 + 4];
    const float cb[8] = { cb0.x, cb0.y, cb0.z, cb0.w, cb1.x, cb1.y, cb1.z, cb1.w };
    const float gg[8] = { g0.x, g0.y, g0.z, g0.w, g1.x, g1.y, g1.z, g1.w };
    const float bb[8] = { b0_.x, b0_.y, b0_.z, b0_.w, b1_.x, b1_.y, b1_.z, b1_.w };
    float v[8];
    #pragma unroll
    for (int j = 0; j < 8; ++j)
        v[j] = fmaxf((acc[j] * dv + cb[j]) * (gg[j] * bnscale) + bb[j], 0.0f);

    if constexpr (!HEAD) {
        if (par == 0) {
            size_t o = ((size_t)n << 6) + f0;
            if constexpr (RES) {
                h8 old = *(const h8*)&hA[o];
                #pragma unroll
                for (int j = 0; j < 8; ++j) v[j] += (float)old[j];
            }
            h8 res = { (_Float16)v[0], (_Float16)v[1], (_Float16)v[2], (_Float16)v[3],
                       (_Float16)v[4], (_Float16)v[5], (_Float16)v[6], (_Float16)v[7] };
            *(h8*)&hA[o] = res;
        }
    } else {
        float p[3];
        #pragma unroll
        for (int o = 0; o < 3; ++o) {
            float t = 0.f;
            #pragma unroll
            for (int j = 0; j < 8; ++j) t += v[j] * HWs[o * 67 + f0 + j];
            p[o] = t;
        }
        #pragma unroll
        for (int mask = 1; mask < 8; mask <<= 1) {
            #pragma unroll
            for (int o = 0; o < 3; ++o) p[o] += __shfl_xor(p[o], mask, 64);
        }
        if ((lane & 15) == 0) {
            float by0 = byp[n * 3], by1 = byp[n * 3 + 1], by2 = byp[n * 3 + 2];
            #pragma unroll
            for (int o = 0; o < 3; ++o)
                p[o] += by0 * HWs[o * 67 + 64] + by1 * HWs[o * 67 + 65] + by2 * HWs[o * 67 + 66]
                      + HWs[201 + o];
            float kappa = fminf(fmaxf(p[0] * 5.0f + 2.5f, 0.2f), 10.0f);
            float tau   = fminf(fmaxf(p[2] + 0.5f, 0.05f), 2.0f);
            out[(size_t)n * 3]     = kappa;
            out[(size_t)n * 3 + 1] = p[1];
            out[(size_t)n * 3 + 2] = tau;
        }
    }
}

extern "C" void kernel_launch(void* const* d_in, const int* in_sizes, int n_in,
                              void* d_out, int out_size, void* d_ws, size_t ws_size,
                              hipStream_t stream) {
    const float* x     = (const float*)d_in[0];
    const int*   ei    = (const int*)d_in[1];
    const int*   row   = ei;
    const int*   col   = ei + NE;
    const float* projW = (const float*)d_in[2];
    const float* projb = (const float*)d_in[3];
    const float* convW[3] = { (const float*)d_in[4], (const float*)d_in[8],  (const float*)d_in[12] };
    const float* convb[3] = { (const float*)d_in[5], (const float*)d_in[9],  (const float*)d_in[13] };
    const float* bng[3]   = { (const float*)d_in[6], (const float*)d_in[10], (const float*)d_in[14] };
    const float* bnb[3]   = { (const float*)d_in[7], (const float*)d_in[11], (const float*)d_in[15] };
    const float* bypW  = (const float*)d_in[16];
    const float* bypb  = (const float*)d_in[17];
    const float* headW = (const float*)d_in[18];
    const float* headb = (const float*)d_in[19];
    float* out = (float*)d_out;

    float*    ws   = (float*)d_ws;
    float*    dinv = ws;                                   // 102400 floats
    _Float16* hAh  = (_Float16*)(ws + 102400);             // NN*64 fp16
    unsigned char* hB8 = (unsigned char*)(hAh + (size_t)NN * 64);  // NN*64 bytes fp8
    float*    byp  = (float*)(hB8 + (size_t)NN * 64);      // NN*3 (+pad 300032)
    int*      off     = (int*)(byp + 300032);              // NN+1 (pad 100096)
    int*      csr_row = off + 100096;                      // NE
    int*      bcnt    = csr_row + NE;                      // NBUK+1 (pad 784)
    int*      blkcnt  = bcnt + 784;                        // NBUK*NCHUNK = 400384
    unsigned* tmp     = (unsigned*)hAh;                    // aliases hAh (consumed before proj)

    // deterministic bucketed CSR build (+dinv +off) — zero global atomics
    k_bucketA<<<NCHUNK, 256, 0, stream>>>(col, blkcnt);
    k_colscan<<<NBUK, NCHUNK, 0, stream>>>(blkcnt, bcnt);
    k_bscan<<<1, 1024, 0, stream>>>(bcnt);
    k_bucketB<<<NCHUNK, 256, 0, stream>>>(row, col, bcnt, blkcnt, tmp);
    k_build<<<NBUK, 256, 0, stream>>>(tmp, bcnt, off, dinv, csr_row);

    // fused proj + byp + conv1: hAh, byp, hB8 in one pass
    k_gemmPC<<<(NN + 63) / 64, 256, 0, stream>>>(
        x, projW, projb, hAh, bypW, bypb, byp, convW[0], dinv, hB8, NN);

    for (int l = 0; l < 3; l++) {
        if (l > 0)   // hB8 = fp8((hAh @ convW.T) * dinv)
            k_gemmC<<<(NN + 63) / 64, 256, 0, stream>>>(hAh, convW[l], dinv, hB8, NN);
        if (l < 2)
            k_gather<true, false><<<NN / 16, 256, 0, stream>>>(
                hB8, dinv, off, csr_row, convb[l], bng[l], bnb[l], hAh,
                nullptr, nullptr, nullptr, nullptr);
        else
            k_gather<false, true><<<NN / 16, 256, 0, stream>>>(
                hB8, dinv, off, csr_row, convb[l], bng[l], bnb[l], nullptr,
                byp, headW, headb, out);
    }
}

// Round 23
// 258.093 us; speedup vs baseline: 1.0188x; 1.0188x over previous
//
#include <hip/hip_runtime.h>
#include <hip/hip_fp16.h>

#define NN 100000
#define NE 1200000
#define NBUK ((NN + 127) / 128)   // 782
#define NCHUNK 512                // chunks in bucket passes

typedef _Float16 h8 __attribute__((ext_vector_type(8)));
typedef float f32x4 __attribute__((ext_vector_type(4)));
typedef float f32x2 __attribute__((ext_vector_type(2)));

// ---------------- deterministic two-phase bucketed CSR build ----------------
__global__ __launch_bounds__(256) void k_bucketA(const int* __restrict__ col,
                                                 int* __restrict__ blkcnt) {
    __shared__ int lh[NBUK];
    const int tid = threadIdx.x;
    const int per = (NE + NCHUNK - 1) / NCHUNK;
    const int e0 = blockIdx.x * per;
    const int e1 = (e0 + per < NE) ? (e0 + per) : NE;
    for (int i = tid; i < NBUK; i += 256) lh[i] = 0;
    __syncthreads();
    for (int e = e0 + tid; e < e1; e += 256)
        atomicAdd(&lh[col[e] >> 7], 1);
    __syncthreads();
    for (int b = tid; b < NBUK; b += 256)
        blkcnt[b * NCHUNK + blockIdx.x] = lh[b];
}

__global__ __launch_bounds__(512) void k_colscan(int* __restrict__ blkcnt, int* __restrict__ bcnt) {
    __shared__ int s[NCHUNK];
    const int b = blockIdx.x, tid = threadIdx.x;
    int v = blkcnt[b * NCHUNK + tid];
    s[tid] = v;
    __syncthreads();
    #pragma unroll
    for (int d = 1; d < NCHUNK; d <<= 1) {
        int t = (tid >= d) ? s[tid - d] : 0;
        __syncthreads();
        s[tid] += t;
        __syncthreads();
    }
    blkcnt[b * NCHUNK + tid] = s[tid] - v;   // exclusive prefix within bucket
    if (tid == NCHUNK - 1) bcnt[b] = s[NCHUNK - 1];
}

__global__ __launch_bounds__(1024) void k_bscan(int* __restrict__ bcnt) {
    __shared__ int s[1024];
    int tid = threadIdx.x;
    int v = (tid < NBUK) ? bcnt[tid] : 0;
    s[tid] = v;
    __syncthreads();
    #pragma unroll
    for (int d = 1; d < 1024; d <<= 1) {
        int t = (tid >= d) ? s[tid - d] : 0;
        __syncthreads();
        s[tid] += t;
        __syncthreads();
    }
    if (tid < NBUK) bcnt[tid] = s[tid] - v;
    if (tid == 0) bcnt[NBUK] = NE;
}

__global__ __launch_bounds__(256) void k_bucketB(const int* __restrict__ row,
                                                 const int* __restrict__ col,
                                                 const int* __restrict__ bbase,
                                                 const int* __restrict__ blkcnt,
                                                 unsigned* __restrict__ tmp) {
    __shared__ int lh[NBUK];
    const int tid = threadIdx.x;
    const int per = (NE + NCHUNK - 1) / NCHUNK;
    const int e0 = blockIdx.x * per;
    const int e1 = (e0 + per < NE) ? (e0 + per) : NE;
    for (int b = tid; b < NBUK; b += 256)
        lh[b] = bbase[b] + blkcnt[b * NCHUNK + blockIdx.x];
    __syncthreads();
    for (int e = e0 + tid; e < e1; e += 256) {
        int c = col[e], r = row[e];
        int pos = atomicAdd(&lh[c >> 7], 1);
        tmp[pos] = ((unsigned)r << 7) | (unsigned)(c & 127);
    }
}

__global__ __launch_bounds__(256) void k_build(const unsigned* __restrict__ tmp,
                                               const int* __restrict__ bbase,
                                               int* __restrict__ off,
                                               float* __restrict__ dinv,
                                               int* __restrict__ csr_row) {
    __shared__ int cnt[128], s[128], cur[128];
    const int b = blockIdx.x, tid = threadIdx.x;
    const int colBase = b << 7;
    const int nCols = (NN - colBase < 128) ? (NN - colBase) : 128;
    const int seg0 = bbase[b], seg1 = bbase[b + 1];
    if (tid < 128) cnt[tid] = 0;
    __syncthreads();
    for (int i = seg0 + tid; i < seg1; i += 256)
        atomicAdd(&cnt[tmp[i] & 127], 1);
    __syncthreads();
    if (tid < 128) s[tid] = cnt[tid];
    __syncthreads();
    #pragma unroll
    for (int d = 1; d < 128; d <<= 1) {
        int t = (tid < 128 && tid >= d) ? s[tid - d] : 0;
        __syncthreads();
        if (tid < 128) s[tid] += t;
        __syncthreads();
    }
    if (tid < nCols) {
        int exc = seg0 + s[tid] - cnt[tid];
        off[colBase + tid] = exc;
        cur[tid] = exc;
        dinv[colBase + tid] = rsqrtf((float)cnt[tid] + 1.0f);
    }
    if (b == 0 && tid == 0) off[NN] = NE;
    __syncthreads();
    for (int i = seg0 + tid; i < seg1; i += 256) {
        unsigned v = tmp[i];
        int pos = atomicAdd(&cur[v & 127u], 1);
        csr_row[pos] = (int)(v >> 7);
    }
}

// ---------------- fused proj + byp + conv1 GEMM ----------------
__global__ __launch_bounds__(256) void k_gemmPC(const float* __restrict__ X,
                                                const float* __restrict__ W,
                                                const float* __restrict__ bias,
                                                _Float16* __restrict__ Yh,
                                                const float* __restrict__ bypW,
                                                const float* __restrict__ bypb,
                                                float* __restrict__ bypOut,
                                                const float* __restrict__ convW1,
                                                const float* __restrict__ dinv,
                                                unsigned char* __restrict__ Y8,
                                                int n_nodes) {
    constexpr int D = 128, RS = D + 8, KS = D / 32;
    constexpr int RS2 = 72;               // hA tile row stride (halfs)
    __shared__ _Float16 Xh[64 * RS];
    __shared__ _Float16 Wh[64 * RS];
    const int tid = threadIdx.x;
    const int n0 = blockIdx.x * 64;

    for (int i = tid; i < 64 * (D / 8); i += 256) {
        int j = i / (D / 8), d8 = (i % (D / 8)) * 8;
        const float4* wp = (const float4*)&W[j * D + d8];
        float4 w0 = wp[0], w1 = wp[1];
        h8 h = { (_Float16)w0.x, (_Float16)w0.y, (_Float16)w0.z, (_Float16)w0.w,
                 (_Float16)w1.x, (_Float16)w1.y, (_Float16)w1.z, (_Float16)w1.w };
        *(h8*)&Wh[j * RS + d8] = h;
    }
    for (int i = tid; i < 64 * (D / 8); i += 256) {
        int nl = i / (D / 8), d8 = (i % (D / 8)) * 8;
        int n = n0 + nl; if (n >= n_nodes) n = n_nodes - 1;
        const float4* xp = (const float4*)&X[(size_t)n * D + d8];
        float4 x0 = xp[0], x1 = xp[1];
        h8 h = { (_Float16)x0.x, (_Float16)x0.y, (_Float16)x0.z, (_Float16)x0.w,
                 (_Float16)x1.x, (_Float16)x1.y, (_Float16)x1.z, (_Float16)x1.w };
        *(h8*)&Xh[nl * RS + d8] = h;
    }
    __syncthreads();

    const int wid = tid >> 6, lane = tid & 63;
    const int lm = lane & 15, lq = lane >> 4;
    const int mBase = wid * 16;

    h8 bfrag[4][KS];
    #pragma unroll
    for (int t = 0; t < 4; ++t)
        #pragma unroll
        for (int s = 0; s < KS; ++s)
            bfrag[t][s] = *(const h8*)&Wh[(t * 16 + lm) * RS + s * 32 + lq * 8];

    h8 bfragB[KS];
    #pragma unroll
    for (int s = 0; s < KS; ++s) {
        if (lm < 3) {
            const float4* wp = (const float4*)&bypW[lm * D + s * 32 + lq * 8];
            float4 w0 = wp[0], w1 = wp[1];
            bfragB[s] = (h8){ (_Float16)w0.x, (_Float16)w0.y, (_Float16)w0.z, (_Float16)w0.w,
                              (_Float16)w1.x, (_Float16)w1.y, (_Float16)w1.z, (_Float16)w1.w };
        } else {
            bfragB[s] = (h8)(_Float16)0;
        }
    }

    f32x4 acc[5] = {};
    #pragma unroll
    for (int s = 0; s < KS; ++s) {
        h8 a = *(const h8*)&Xh[(mBase + lm) * RS + s * 32 + lq * 8];
        #pragma unroll
        for (int t = 0; t < 4; ++t)
            acc[t] = __builtin_amdgcn_mfma_f32_16x16x32_f16(a, bfrag[t][s], acc[t], 0, 0, 0);
        acc[4] = __builtin_amdgcn_mfma_f32_16x16x32_f16(a, bfragB[s], acc[4], 0, 0, 0);
    }

    float bb[4];
    #pragma unroll
    for (int t = 0; t < 4; ++t) bb[t] = bias[t * 16 + lm];
    float bypbv = (lm < 3) ? bypb[lm] : 0.f;
    const int nodeBase = n0 + mBase + lq * 4;

    __syncthreads();   // all waves done reading Xh/Wh; safe to repurpose

    #pragma unroll
    for (int r = 0; r < 4; ++r) {
        int node = nodeBase + r;
        int nloc = mBase + lq * 4 + r;
        #pragma unroll
        for (int t = 0; t < 4; ++t) {
            _Float16 hv = (_Float16)(acc[t][r] + bb[t]);
            Xh[nloc * RS2 + t * 16 + lm] = hv;            // stash tile
            if (node < n_nodes)
                Yh[(size_t)node * 64 + t * 16 + lm] = hv;
        }
        if (node < n_nodes && lm < 3)
            bypOut[node * 3 + lm] = acc[4][r] + bypbv;
    }
    for (int i = tid; i < 64 * 8; i += 256) {
        int j = i >> 3, d8 = (i & 7) * 8;
        const float4* wp = (const float4*)&convW1[j * 64 + d8];
        float4 w0 = wp[0], w1 = wp[1];
        h8 h = { (_Float16)w0.x, (_Float16)w0.y, (_Float16)w0.z, (_Float16)w0.w,
                 (_Float16)w1.x, (_Float16)w1.y, (_Float16)w1.z, (_Float16)w1.w };
        *(h8*)&Wh[j * RS2 + d8] = h;
    }
    __syncthreads();

    h8 cfrag[4][2];
    #pragma unroll
    for (int t = 0; t < 4; ++t)
        #pragma unroll
        for (int s = 0; s < 2; ++s)
            cfrag[t][s] = *(const h8*)&Wh[(t * 16 + lm) * RS2 + s * 32 + lq * 8];

    f32x4 acc2[4] = {};
    #pragma unroll
    for (int s = 0; s < 2; ++s) {
        h8 a = *(const h8*)&Xh[(mBase + lm) * RS2 + s * 32 + lq * 8];
        #pragma unroll
        for (int t = 0; t < 4; ++t)
            acc2[t] = __builtin_amdgcn_mfma_f32_16x16x32_f16(a, cfrag[t][s], acc2[t], 0, 0, 0);
    }
    #pragma unroll
    for (int r = 0; r < 4; ++r) {
        int node = nodeBase + r;
        if (node < n_nodes) {
            float sdv = dinv[node];
            #pragma unroll
            for (int t = 0; t < 4; ++t) {
                float v = acc2[t][r] * sdv;
                int pk = __builtin_amdgcn_cvt_pk_fp8_f32(v, v, 0, false);
                Y8[(size_t)node * 64 + t * 16 + lm] = (unsigned char)(pk & 0xff);
            }
        }
    }
}

// ---------------- conv GEMM (D=64): fp8 e4m3 message output only ----------------
__global__ __launch_bounds__(256) void k_gemmC(const _Float16* __restrict__ Xhg,
                                               const float* __restrict__ W,
                                               const float* __restrict__ dinv,
                                               unsigned char* __restrict__ Y8,
                                               int n_nodes) {
    constexpr int D = 64, RS = D + 8, KS = D / 32;
    __shared__ _Float16 Xh[64 * RS];
    __shared__ _Float16 Wh[64 * RS];
    const int tid = threadIdx.x;
    const int n0 = blockIdx.x * 64;

    for (int i = tid; i < 64 * (D / 8); i += 256) {
        int j = i / (D / 8), d8 = (i % (D / 8)) * 8;
        const float4* wp = (const float4*)&W[j * D + d8];
        float4 w0 = wp[0], w1 = wp[1];
        h8 h = { (_Float16)w0.x, (_Float16)w0.y, (_Float16)w0.z, (_Float16)w0.w,
                 (_Float16)w1.x, (_Float16)w1.y, (_Float16)w1.z, (_Float16)w1.w };
        *(h8*)&Wh[j * RS + d8] = h;
    }
    for (int i = tid; i < 64 * (D / 8); i += 256) {
        int nl = i / (D / 8), d8 = (i % (D / 8)) * 8;
        int n = n0 + nl; if (n >= n_nodes) n = n_nodes - 1;
        *(h8*)&Xh[nl * RS + d8] = *(const h8*)&Xhg[(size_t)n * D + d8];
    }
    __syncthreads();

    const int wid = tid >> 6, lane = tid & 63;
    const int lm = lane & 15, lq = lane >> 4;
    const int mBase = wid * 16;

    h8 bfrag[4][KS];
    #pragma unroll
    for (int t = 0; t < 4; ++t)
        #pragma unroll
        for (int s = 0; s < KS; ++s)
            bfrag[t][s] = *(const h8*)&Wh[(t * 16 + lm) * RS + s * 32 + lq * 8];

    f32x4 acc[4] = {};
    #pragma unroll
    for (int s = 0; s < KS; ++s) {
        h8 a = *(const h8*)&Xh[(mBase + lm) * RS + s * 32 + lq * 8];
        #pragma unroll
        for (int t = 0; t < 4; ++t)
            acc[t] = __builtin_amdgcn_mfma_f32_16x16x32_f16(a, bfrag[t][s], acc[t], 0, 0, 0);
    }

    const int nodeBase = n0 + mBase + lq * 4;
    #pragma unroll
    for (int r = 0; r < 4; ++r) {
        int node = nodeBase + r;
        if (node < n_nodes) {
            float sdv = dinv[node];
            #pragma unroll
            for (int t = 0; t < 4; ++t) {
                float v = acc[t][r] * sdv;
                int pk = __builtin_amdgcn_cvt_pk_fp8_f32(v, v, 0, false);
                Y8[(size_t)node * 64 + t * 16 + lm] = (unsigned char)(pk & 0xff);
            }
        }
    }
}

// ---------------- pull-aggregation: fp8 messages (incl. self), fp32 acc, 8-wide MLP ----------------
template<bool RES, bool HEAD>
__global__ __launch_bounds__(256) void k_gather(const unsigned char* __restrict__ hB8,
                                                const float* __restrict__ dinv,
                                                const int* __restrict__ off,
                                                const int* __restrict__ csr_row,
                                                const float* __restrict__ convb,
                                                const float* __restrict__ bng,
                                                const float* __restrict__ bnb,
                                                _Float16* __restrict__ hA,
                                                const float* __restrict__ byp,
                                                const float* __restrict__ headW,
                                                const float* __restrict__ headb,
                                                float* __restrict__ out) {
    __shared__ float HWs[HEAD ? 204 : 1];
    const int tid = threadIdx.x;
    if constexpr (HEAD) {
        for (int i = tid; i < 204; i += 256)
            HWs[i] = (i < 201) ? headW[i] : headb[i - 201];
        __syncthreads();
    }
    const int wid = tid >> 6, lane = tid & 63;
    const int n = blockIdx.x * 32 + wid * 8 + (lane >> 3);   // grid = NN/32 exactly
    const int oct = lane & 7;
    const int f0 = oct * 8;

    const int e0 = off[n], eEnd = off[n + 1];
    const int deg = eEnd - e0;
    int m = deg;
    #pragma unroll
    for (int mask = 8; mask < 64; mask <<= 1) {
        int o = __shfl_xor(m, mask, 64);
        m = (o > m) ? o : m;
    }

    const uint2* rows8 = (const uint2*)hB8;   // 8 uint2 per node row
    float acc[8] = {0, 0, 0, 0, 0, 0, 0, 0};
    uint2 selfw = rows8[(size_t)n * 8 + oct];
    {
        f32x2 p0 = __builtin_amdgcn_cvt_pk_f32_fp8(selfw.x, false);
        f32x2 p1 = __builtin_amdgcn_cvt_pk_f32_fp8(selfw.x, true);
        f32x2 p2 = __builtin_amdgcn_cvt_pk_f32_fp8(selfw.y, false);
        f32x2 p3 = __builtin_amdgcn_cvt_pk_f32_fp8(selfw.y, true);
        acc[0] += p0.x; acc[1] += p0.y; acc[2] += p1.x; acc[3] += p1.y;
        acc[4] += p2.x; acc[5] += p2.y; acc[6] += p3.x; acc[7] += p3.y;
    }
    for (int it = 0; it < m; it += 8) {
        uint2 w[8];
        #pragma unroll
        for (int q = 0; q < 8; ++q) {
            bool vq = it + q < deg;
            int rq = csr_row[vq ? e0 + it + q : 0];
            w[q] = rows8[(size_t)rq * 8 + oct];
            if (!vq) { w[q].x = 0; w[q].y = 0; }
        }
        #pragma unroll
        for (int q = 0; q < 8; ++q) {
            f32x2 p0 = __builtin_amdgcn_cvt_pk_f32_fp8(w[q].x, false);
            f32x2 p1 = __builtin_amdgcn_cvt_pk_f32_fp8(w[q].x, true);
            f32x2 p2 = __builtin_amdgcn_cvt_pk_f32_fp8(w[q].y, false);
            f32x2 p3 = __builtin_amdgcn_cvt_pk_f32_fp8(w[q].y, true);
            acc[0] += p0.x; acc[1] += p0.y; acc[2] += p1.x; acc[3] += p1.y;
            acc[4] += p2.x; acc[5] += p2.y; acc[6] += p3.x; acc[7] += p3.y;
        }
    }

    const float dv = dinv[n];
    const float bnscale = rsqrtf(1.0f + 1e-5f);
    const float4 cb0 = *(const float4*)&convb[f0], cb1 = *(const float4*)&convb[f0 + 4];
    const float4 g0  = *(const float4*)&bng[f0],  g1  = *(const float4*)&bng[f0 + 4];
    const float4 b0_ = *(const float4*)&bnb[f0],  b1_ = *(const float4*)&bnb[f0 + 4];
    const float cb[8] = { cb0.x, cb0.y, cb0.z, cb0.w, cb1.x, cb1.y, cb1.z, cb1.w };
    const float gg[8] = { g0.x, g0.y, g0.z, g0.w, g1.x, g1.y, g1.z, g1.w };
    const float bb[8] = { b0_.x, b0_.y, b0_.z, b0_.w, b1_.x, b1_.y, b1_.z, b1_.w };
    float v[8];
    #pragma unroll
    for (int j = 0; j < 8; ++j)
        v[j] = fmaxf((acc[j] * dv + cb[j]) * (gg[j] * bnscale) + bb[j], 0.0f);

    if constexpr (!HEAD) {
        size_t o = ((size_t)n << 6) + f0;
        if constexpr (RES) {
            h8 old = *(const h8*)&hA[o];
            #pragma unroll
            for (int j = 0; j < 8; ++j) v[j] += (float)old[j];
        }
        h8 res = { (_Float16)v[0], (_Float16)v[1], (_Float16)v[2], (_Float16)v[3],
                   (_Float16)v[4], (_Float16)v[5], (_Float16)v[6], (_Float16)v[7] };
        *(h8*)&hA[o] = res;
    } else {
        float p[3];
        #pragma unroll
        for (int o = 0; o < 3; ++o) {
            float t = 0.f;
            #pragma unroll
            for (int j = 0; j < 8; ++j) t += v[j] * HWs[o * 67 + f0 + j];
            p[o] = t;
        }
        #pragma unroll
        for (int mask = 1; mask < 8; mask <<= 1) {
            #pragma unroll
            for (int o = 0; o < 3; ++o) p[o] += __shfl_xor(p[o], mask, 64);
        }
        if (oct == 0) {
            float by0 = byp[n * 3], by1 = byp[n * 3 + 1], by2 = byp[n * 3 + 2];
            #pragma unroll
            for (int o = 0; o < 3; ++o)
                p[o] += by0 * HWs[o * 67 + 64] + by1 * HWs[o * 67 + 65] + by2 * HWs[o * 67 + 66]
                      + HWs[201 + o];
            float kappa = fminf(fmaxf(p[0] * 5.0f + 2.5f, 0.2f), 10.0f);
            float tau   = fminf(fmaxf(p[2] + 0.5f, 0.05f), 2.0f);
            out[(size_t)n * 3]     = kappa;
            out[(size_t)n * 3 + 1] = p[1];
            out[(size_t)n * 3 + 2] = tau;
        }
    }
}

extern "C" void kernel_launch(void* const* d_in, const int* in_sizes, int n_in,
                              void* d_out, int out_size, void* d_ws, size_t ws_size,
                              hipStream_t stream) {
    const float* x     = (const float*)d_in[0];
    const int*   ei    = (const int*)d_in[1];
    const int*   row   = ei;
    const int*   col   = ei + NE;
    const float* projW = (const float*)d_in[2];
    const float* projb = (const float*)d_in[3];
    const float* convW[3] = { (const float*)d_in[4], (const float*)d_in[8],  (const float*)d_in[12] };
    const float* convb[3] = { (const float*)d_in[5], (const float*)d_in[9],  (const float*)d_in[13] };
    const float* bng[3]   = { (const float*)d_in[6], (const float*)d_in[10], (const float*)d_in[14] };
    const float* bnb[3]   = { (const float*)d_in[7], (const float*)d_in[11], (const float*)d_in[15] };
    const float* bypW  = (const float*)d_in[16];
    const float* bypb  = (const float*)d_in[17];
    const float* headW = (const float*)d_in[18];
    const float* headb = (const float*)d_in[19];
    float* out = (float*)d_out;

    float*    ws   = (float*)d_ws;
    float*    dinv = ws;                                   // 102400 floats
    _Float16* hAh  = (_Float16*)(ws + 102400);             // NN*64 fp16
    unsigned char* hB8 = (unsigned char*)(hAh + (size_t)NN * 64);  // NN*64 bytes fp8
    float*    byp  = (float*)(hB8 + (size_t)NN * 64);      // NN*3 (+pad 300032)
    int*      off     = (int*)(byp + 300032);              // NN+1 (pad 100096)
    int*      csr_row = off + 100096;                      // NE
    int*      bcnt    = csr_row + NE;                      // NBUK+1 (pad 784)
    int*      blkcnt  = bcnt + 784;                        // NBUK*NCHUNK = 400384
    unsigned* tmp     = (unsigned*)hAh;                    // aliases hAh (consumed before proj)

    // deterministic bucketed CSR build (+dinv +off) — zero global atomics
    k_bucketA<<<NCHUNK, 256, 0, stream>>>(col, blkcnt);
    k_colscan<<<NBUK, NCHUNK, 0, stream>>>(blkcnt, bcnt);
    k_bscan<<<1, 1024, 0, stream>>>(bcnt);
    k_bucketB<<<NCHUNK, 256, 0, stream>>>(row, col, bcnt, blkcnt, tmp);
    k_build<<<NBUK, 256, 0, stream>>>(tmp, bcnt, off, dinv, csr_row);

    // fused proj + byp + conv1: hAh, byp, hB8 in one pass
    k_gemmPC<<<(NN + 63) / 64, 256, 0, stream>>>(
        x, projW, projb, hAh, bypW, bypb, byp, convW[0], dinv, hB8, NN);

    for (int l = 0; l < 3; l++) {
        if (l > 0)   // hB8 = fp8((hAh @ convW.T) * dinv)
            k_gemmC<<<(NN + 63) / 64, 256, 0, stream>>>(hAh, convW[l], dinv, hB8, NN);
        if (l < 2)
            k_gather<true, false><<<NN / 32, 256, 0, stream>>>(
                hB8, dinv, off, csr_row, convb[l], bng[l], bnb[l], hAh,
                nullptr, nullptr, nullptr, nullptr);
        else
            k_gather<false, true><<<NN / 32, 256, 0, stream>>>(
                hB8, dinv, off, csr_row, convb[l], bng[l], bnb[l], nullptr,
                byp, headW, headb, out);
    }
}